// Round 10
// baseline (1899.338 us; speedup 1.0000x reference)
//
#include <hip/hip_runtime.h>
#include <math.h>

#define NX 192
#define NY 192
#define NZ 96
#define NV 4
#define VOL (NZ * NY * NX)      /* 3,538,944 */
#define NTOT (NV * VOL)         /* 14,155,776 */
#define YS NX
#define ZS (NY * NX)

/* ---- single-round (LAST) kernel geometry — round-3 verified ---- */
#define TX 48
#define TY 16
#define ZCH 24
#define NG 14
#define AROWS (TY + 4)
#define EROWS (TY + 2)
#define AJOBS (AROWS * NG)
#define EJOBS (EROWS * NG)
#define UJOBS (TY * (TX / 4))

/* ---- double-round kernel geometry (fp16 LDS) — round-9 verified ---- */
#define TY2 12
#define ZCH2 16                  /* 6 z-chunks -> grid 1536 = 6 blocks/CU */
#define R2A 18                   /* A rows: halo 3 */
#define R2E1 16                  /* E1 rows: halo 2 */
#define R2E2 14                  /* E2 rows: halo 1 */

#define SLOT5(x) (((x) + 100) % 5)
#define SLOT4(x) (((x) + 100) % 4)

#define HINF  0x7C00u
#define HNINF 0xFC00u

typedef _Float16 h2v __attribute__((ext_vector_type(2)));

struct __align__(8) H4u { unsigned lo, hi; };   /* 4 fp16: e0(low16 of lo)..e3 */

__device__ __forceinline__ h2v h2_of(unsigned u) { return __builtin_bit_cast(h2v, u); }
__device__ __forceinline__ unsigned u_of(h2v h) { return __builtin_bit_cast(unsigned, h); }

__device__ __forceinline__ H4u h4min(H4u a, H4u b) {
    H4u r;
    r.lo = u_of(__builtin_elementwise_min(h2_of(a.lo), h2_of(b.lo)));
    r.hi = u_of(__builtin_elementwise_min(h2_of(a.hi), h2_of(b.hi)));
    return r;
}
__device__ __forceinline__ H4u h4max(H4u a, H4u b) {
    H4u r;
    r.lo = u_of(__builtin_elementwise_max(h2_of(a.lo), h2_of(b.lo)));
    r.hi = u_of(__builtin_elementwise_max(h2_of(a.hi), h2_of(b.hi)));
    return r;
}
/* [p, e0, e1, e2] : left-neighbor vector (p16 = prev element, low 16 bits) */
__device__ __forceinline__ H4u shl1(H4u c, unsigned p16) {
    H4u r;
    r.lo = (c.lo << 16) | (p16 & 0xFFFFu);
    r.hi = (c.hi << 16) | (c.lo >> 16);
    return r;
}
/* [e1, e2, e3, n] : right-neighbor vector */
__device__ __forceinline__ H4u shr1(H4u c, unsigned n16) {
    H4u r;
    r.lo = (c.lo >> 16) | (c.hi << 16);
    r.hi = (c.hi >> 16) | ((n16 & 0xFFFFu) << 16);
    return r;
}
__device__ __forceinline__ H4u f4_to_h4(float4 f) {
    h2v a, b;
    a[0] = (_Float16)f.x; a[1] = (_Float16)f.y;
    b[0] = (_Float16)f.z; b[1] = (_Float16)f.w;
    H4u r; r.lo = u_of(a); r.hi = u_of(b); return r;
}
__device__ __forceinline__ float4 h4_to_f4(H4u h) {
    h2v a = h2_of(h.lo), b = h2_of(h.hi);
    return make_float4((float)a[0], (float)a[1], (float)b[0], (float)b[1]);
}

__device__ __forceinline__ float4 min4(float4 a, float4 b) {
    return make_float4(fminf(a.x, b.x), fminf(a.y, b.y),
                       fminf(a.z, b.z), fminf(a.w, b.w));
}
__device__ __forceinline__ float4 max4(float4 a, float4 b) {
    return make_float4(fmaxf(a.x, b.x), fmaxf(a.y, b.y),
                       fmaxf(a.z, b.z), fmaxf(a.w, b.w));
}
__device__ __forceinline__ float4 win3max(float a, float4 b, float c) {
    return make_float4(fmaxf(fmaxf(a, b.x), b.y),
                       fmaxf(fmaxf(b.x, b.y), b.z),
                       fmaxf(fmaxf(b.y, b.z), b.w),
                       fmaxf(fmaxf(b.z, b.w), c));
}

// ---------------- double-round kernel, fp16 LDS + fp16 skel ----------------
// Round-9-verified skewed pipeline (1 barrier/step): E1(z+1), {E2+upd1}(z-1),
// upd2(z-3).  All morphology in packed fp16 (exact for min/max); skel update
// math in f32, storage fp16 (one rounding per launch).
template<bool FIRST>
__global__ __launch_bounds__(256, 6) void fused2_kernel(
    const float* __restrict__ pred, const float* __restrict__ target,
    const _Float16* __restrict__ Ain, _Float16* __restrict__ Eout,
    _Float16* __restrict__ skel)
{
    __shared__ H4u As[5][R2A][NG];
    __shared__ H4u E1s[5][R2E1][NG];
    __shared__ H4u E2s[4][R2E2][NG];

    const int tid = threadIdx.x;
    const int lr  = tid >> 4;               /* row lane 0..15 */
    const int c   = tid & 15;               /* col group 0..15 (0..13 real) */
    const int cc  = (c < 14) ? c : 13;
    const int sr  = tid / 14;               /* stage row 0..18 (252 active) */
    const int sg  = tid - sr * 14;

    const int x0 = blockIdx.x * TX;
    const int y0 = blockIdx.y * TY2;
    const int v  = blockIdx.z / 6;
    const int ch = blockIdx.z % 6;
    const int z0 = ch * ZCH2;
    const int z1 = z0 + ZCH2;

    const float* Af = nullptr;
    const _Float16* Ah = nullptr;
    if (FIRST) Af = ((v < 2) ? pred : target) + (size_t)((v & 1) * 2 + 1) * VOL;
    else       Ah = Ain + (size_t)v * VOL;
    _Float16* Ev = Eout + (size_t)v * VOL;
    _Float16* Sv = skel + (size_t)v * VOL;

    const H4u HP4 = { 0x7C007C00u, 0x7C007C00u };   /* +inf x4 */
    const H4u HN4 = { 0xFC00FC00u, 0xFC00FC00u };   /* -inf x4 */
    const float4 ZERO4 = make_float4(0.f, 0.f, 0.f, 0.f);

    const bool xlo = (x0 == 0);
    const bool xhi = (x0 + TX == NX);

    const int  gys  = y0 - 3 + sr;
    const int  gxs  = x0 - 4 + 4 * sg;
    const bool stIn = (sr < R2A) && (gys >= 0) && (gys < NY) &&
                      (gxs >= 0) && (gxs < NX);

    const int  gx   = x0 - 4 + 4 * c;
    const bool gxin = (c < 14) && (gx >= 0) && (gx < NX);
    const int  gyu  = y0 + lr - 1;          /* update-cell row */
    const bool uAct = (lr >= 1 && lr <= 12 && c >= 1 && c <= 12);

    auto stageLoad = [&](int za) -> H4u {
        H4u val = HP4;
        if (stIn && za >= 0 && za < NZ) {
            if (FIRST)
                val = f4_to_h4(*(const float4*)(Af + (size_t)za * ZS + gys * YS + gxs));
            else
                val = *(const H4u*)(Ah + (size_t)za * ZS + gys * YS + gxs);
        }
        return val;
    };
    auto stageWrite = [&](int za, H4u val) {
        if (sr < R2A) As[SLOT5(za)][sr][sg] = val;
    };

    auto e1compute = [&](int zp) {          /* E1 plane zp, rows 0..15 */
        const int s_c = SLOT5(zp);
        const int s_m = SLOT5(zp - 1);
        const int s_p = SLOT5(zp + 1);
        const bool hp = (zp + 1 < NZ);
        const int ar = lr + 1;
        H4u cen = As[s_c][ar][cc];
        H4u ylo = As[s_c][ar - 1][cc];
        H4u yhi = As[s_c][ar + 1][cc];
        H4u zlo = As[s_m][ar][cc];
        H4u zhi = hp ? As[s_p][ar][cc] : HP4;
        unsigned lw = __shfl_up(cen.hi, 1) >> 16;
        unsigned rx = __shfl_down(cen.lo, 1) & 0xFFFFu;
        if (c == 0) lw = HINF;
        H4u m = h4min(cen, shl1(cen, lw));
        m = h4min(m, shr1(cen, rx));
        m = h4min(m, h4min(ylo, yhi));
        m = h4min(m, h4min(zlo, zhi));
        const int gy = y0 - 2 + lr;
        if (zp < 0 || gy < 0 || gy >= NY || !gxin) m = HP4;
        if (c < 14) E1s[s_c][lr][c] = m;
    };

    // ---- prologue: A(z0-3..z0+2), E1(z0-2..z0) ----
    stageWrite(z0 - 3, stageLoad(z0 - 3));
    stageWrite(z0 - 2, stageLoad(z0 - 2));
    stageWrite(z0 - 1, stageLoad(z0 - 1));
    stageWrite(z0,     stageLoad(z0));
    stageWrite(z0 + 1, stageLoad(z0 + 1));
    __syncthreads();
    e1compute(z0 - 2);
    e1compute(z0 - 1);
    __syncthreads();
    stageWrite(z0 + 2, stageLoad(z0 + 2));
    e1compute(z0);
    __syncthreads();

    float4 skA = ZERO4, sq1 = ZERO4, sq2 = ZERO4;

    // ---- main loop: one barrier per step ----
    for (int z = z0; z <= z1 + 2; ++z) {
        /* issue global loads early: next A plane + skel for plane z */
        const bool doStage = (z <= z1 - 1);
        H4u stv = doStage ? stageLoad(z + 3) : HP4;
        float4 skN = ZERO4;
        if (!FIRST && z < z1 && uAct)
            skN = h4_to_f4(*(const H4u*)(Sv + (size_t)z * ZS + gyu * YS + gx));

        /* E1(z+1) */
        if (z + 1 <= z1 + 1 && z + 1 < NZ) e1compute(z + 1);

        /* merged E2(p) + upd1(p), p = z-1 */
        const int p = z - 1;
        const bool doE2 = (p >= 0) && (p <= z1) && (p < NZ);
        const bool doU1 = (p >= z0) && (p < z1);
        float4 spnew = ZERO4;
        if (doE2 || doU1) {
            const int s0 = SLOT5(p - 1);
            const int s1 = SLOT5(p);
            const int s2 = SLOT5(p + 1);
            const bool zok0 = (p - 1 >= 0);
            const bool zok2 = (p + 1 < NZ);
            const int r = (lr < R2E2) ? lr : (R2E2 - 1);
            H4u e00 = E1s[s0][r][cc], e01 = E1s[s0][r + 1][cc], e02 = E1s[s0][r + 2][cc];
            H4u e10 = E1s[s1][r][cc], e11 = E1s[s1][r + 1][cc], e12 = E1s[s1][r + 2][cc];
            H4u e20 = E1s[s2][r][cc], e21 = E1s[s2][r + 1][cc], e22 = E1s[s2][r + 2][cc];

            /* ---- E2 erode (plane p, row gy = y0-1+lr) ---- */
            {
                H4u zhiE = zok2 ? e21 : HP4;
                unsigned lwE = __shfl_up(e11.hi, 1) >> 16;
                unsigned rxE = __shfl_down(e11.lo, 1) & 0xFFFFu;
                if (c == 0) lwE = HINF;
                H4u m2 = h4min(e11, shl1(e11, lwE));
                m2 = h4min(m2, shr1(e11, rxE));
                m2 = h4min(m2, h4min(e10, e12));
                m2 = h4min(m2, h4min(e01, zhiE));
                const int gyE = y0 - 1 + lr;
                bool oob = (gyE < 0) || (gyE >= NY) || !gxin;
                H4u m2st = oob ? HN4 : m2;
                if (lr < R2E2 && c < 14) {
                    E2s[SLOT4(p)][lr][c] = m2st;
                    if (p >= z0 && p < z1 && lr >= 1 && lr <= 12 && c >= 1 && c <= 12)
                        *(H4u*)(Ev + (size_t)p * ZS + gyE * YS + gx) = m2;
                }
            }

            /* ---- upd1: delta = relu(A(p) - dilate(E1)(p)) ---- */
            if (doU1) {
                H4u r0 = h4max(zok0 ? e00 : HN4, h4max(e10, zok2 ? e20 : HN4));
                H4u r1 = h4max(zok0 ? e01 : HN4, h4max(e11, zok2 ? e21 : HN4));
                H4u r2 = h4max(zok0 ? e02 : HN4, h4max(e12, zok2 ? e22 : HN4));
                bool oy0 = (y0 - 2 + r < 0) || (y0 - 2 + r >= NY);
                bool oy1 = (y0 - 1 + r < 0) || (y0 - 1 + r >= NY);
                bool oy2 = (y0 + r >= NY);
                if (oy0) r0 = HN4;
                if (oy1) r1 = HN4;
                if (oy2) r2 = HN4;
                H4u vm = h4max(r0, h4max(r1, r2));
                unsigned lw = __shfl_up(vm.hi, 1) >> 16;
                unsigned rx = __shfl_down(vm.lo, 1) & 0xFFFFu;
                if (xlo && c == 1)  lw = HNINF;
                if (xhi && c == 12) rx = HNINF;
                if (uAct) {
                    H4u dilh = h4max(h4max(shl1(vm, lw), vm), shr1(vm, rx));
                    float4 dil = h4_to_f4(dilh);
                    float4 a = h4_to_f4(As[s1][lr + 2][cc]);
                    float4 s = skA;
                    float dd;
                    dd = fmaxf(a.x - dil.x, 0.f); s.x += fmaxf(dd - s.x * dd, 0.f);
                    dd = fmaxf(a.y - dil.y, 0.f); s.y += fmaxf(dd - s.y * dd, 0.f);
                    dd = fmaxf(a.z - dil.z, 0.f); s.z += fmaxf(dd - s.z * dd, 0.f);
                    dd = fmaxf(a.w - dil.w, 0.f); s.w += fmaxf(dd - s.w * dd, 0.f);
                    spnew = s;
                }
            }
        }

        /* ---- upd2(q): delta = relu(E1(q) - dilate(E2)(q)), q = z-3 ---- */
        const int q = z - 3;
        if (q >= z0 && q < z1) {
            const int t0s = SLOT4(q - 1);
            const int t1s = SLOT4(q);
            const int t2s = SLOT4(q + 1);
            const bool qok0 = (q - 1 >= 0);
            const bool qok2 = (q + 1 < NZ);
            const int rb = (lr >= 1) ? ((lr <= 12) ? lr - 1 : 11) : 0;
            H4u f00 = E2s[t0s][rb][cc], f01 = E2s[t0s][rb + 1][cc], f02 = E2s[t0s][rb + 2][cc];
            H4u f10 = E2s[t1s][rb][cc], f11 = E2s[t1s][rb + 1][cc], f12 = E2s[t1s][rb + 2][cc];
            H4u f20 = E2s[t2s][rb][cc], f21 = E2s[t2s][rb + 1][cc], f22 = E2s[t2s][rb + 2][cc];
            if (!qok0) { f00 = HN4; f01 = HN4; f02 = HN4; }
            if (!qok2) { f20 = HN4; f21 = HN4; f22 = HN4; }
            H4u zq0 = h4max(f00, h4max(f10, f20));
            H4u zq1 = h4max(f01, h4max(f11, f21));
            H4u zq2 = h4max(f02, h4max(f12, f22));
            H4u vm = h4max(zq0, h4max(zq1, zq2));
            unsigned lw = __shfl_up(vm.hi, 1) >> 16;
            unsigned rx = __shfl_down(vm.lo, 1) & 0xFFFFu;
            /* E2s stores -inf pads: no x/y overrides needed */
            if (uAct) {
                H4u dilh = h4max(h4max(shl1(vm, lw), vm), shr1(vm, rx));
                float4 dil = h4_to_f4(dilh);
                const int ra = (lr + 1 < R2E1) ? lr + 1 : (R2E1 - 1);
                float4 a = h4_to_f4(E1s[SLOT5(q)][ra][cc]);
                float4 s = sq2;
                float dd;
                dd = fmaxf(a.x - dil.x, 0.f); s.x += fmaxf(dd - s.x * dd, 0.f);
                dd = fmaxf(a.y - dil.y, 0.f); s.y += fmaxf(dd - s.y * dd, 0.f);
                dd = fmaxf(a.z - dil.z, 0.f); s.z += fmaxf(dd - s.z * dd, 0.f);
                dd = fmaxf(a.w - dil.w, 0.f); s.w += fmaxf(dd - s.w * dd, 0.f);
                *(H4u*)(Sv + (size_t)q * ZS + gyu * YS + gx) = f4_to_h4(s);
            }
        }

        /* commit staged A plane */
        if (doStage) stageWrite(z + 3, stv);

        __syncthreads();
        sq2 = sq1; sq1 = spnew; skA = skN;
    }
}

// ---------------- LAST single-round kernel (round 50 + fused reduction) -----
// Round-3-verified structure; A + skel read fp16; NO skel store (nothing
// reads it afterward); sums accumulated in-register -> block reduce -> atomics.
__global__ __launch_bounds__(256, 3) void fused_last_kernel(
    const _Float16* __restrict__ Ain,
    const float* __restrict__ pred, const float* __restrict__ target,
    const _Float16* __restrict__ skel, double* __restrict__ sums)
{
    __shared__ float4 As[4][AROWS][NG];
    __shared__ float4 Es[3][EROWS][NG];
    __shared__ float4 Ms[EROWS][NG];
    __shared__ double sred[8];

    const int tid = threadIdx.x;
    const int x0 = blockIdx.x * TX;
    const int y0 = blockIdx.y * TY;
    const int v  = blockIdx.z >> 2;
    const int z0 = (blockIdx.z & 3) * ZCH;
    const int z1 = z0 + ZCH;

    const _Float16* Av = Ain + (size_t)v * VOL;
    const _Float16* Sv = skel + (size_t)v * VOL;
    const float* Ov = ((v < 2) ? target : pred) + (size_t)((v & 1) * 2 + 1) * VOL;

    const float4 PINF4 = make_float4(INFINITY, INFINITY, INFINITY, INFINITY);
    const float4 NINF4 = make_float4(-INFINITY, -INFINITY, -INFINITY, -INFINITY);
    const float4 ZERO4 = make_float4(0.f, 0.f, 0.f, 0.f);

    const int ur  = tid / (TX / 4);
    const int ugp = tid - ur * (TX / 4);

    auto stageA = [&](int z) {
        int slot = (z + 8) & 3;
        float4* dst = &As[slot][0][0];
        if (z < 0 || z >= NZ) {
            for (int j = tid; j < AJOBS; j += 256) dst[j] = PINF4;
        } else {
            const _Float16* P = Av + (size_t)z * ZS;
            for (int j = tid; j < AJOBS; j += 256) {
                int r = j / NG, g = j - r * NG;
                int gy = y0 - 2 + r;
                int gx0 = x0 - 4 + 4 * g;
                float4 val = PINF4;
                if (gy >= 0 && gy < NY && gx0 >= 0 && gx0 < NX)
                    val = h4_to_f4(*(const H4u*)(P + gy * YS + gx0));
                dst[j] = val;
            }
        }
    };

    auto eplane = [&](int z) {
        int es = (z + 9) % 3;
        float4* dst = &Es[es][0][0];
        if (z < 0 || z >= NZ) {
            for (int j = tid; j < EJOBS; j += 256) dst[j] = NINF4;
            return;
        }
        const int sc = (z + 8) & 3;
        const int sm = (z + 7) & 3;
        const int sp = (z + 9) & 3;
        for (int j = tid; j < EJOBS; j += 256) {
            int r = j / NG, g = j - r * NG;
            float4 c  = As[sc][r + 1][g];
            float4 yl = As[sc][r][g];
            float4 yh = As[sc][r + 2][g];
            float4 zl = As[sm][r + 1][g];
            float4 zh = As[sp][r + 1][g];
            float pw = (g > 0)      ? As[sc][r + 1][g - 1].w : INFINITY;
            float nx = (g < NG - 1) ? As[sc][r + 1][g + 1].x : INFINITY;
            float4 xl = make_float4(pw, c.x, c.y, c.z);
            float4 xr = make_float4(c.y, c.z, c.w, nx);
            float4 m = min4(c, xl);
            m = min4(m, xr);
            m = min4(m, yl);
            m = min4(m, yh);
            m = min4(m, zl);
            m = min4(m, zh);
            int gy = y0 - 1 + r;
            int gx0 = x0 - 4 + 4 * g;
            if (gy < 0 || gy >= NY || gx0 < 0 || gx0 >= NX) m = NINF4;
            dst[j] = m;
        }
    };

    stageA(z0 - 2); stageA(z0 - 1); stageA(z0); stageA(z0 + 1);
    __syncthreads();
    eplane(z0 - 1);
    eplane(z0);
    __syncthreads();
    stageA(z0 + 2);
    __syncthreads();

    double afd = 0.0, afs = 0.0;

    for (int z = z0; z < z1; ++z) {
        float4 oCur = ZERO4;
        if (tid < UJOBS)
            oCur = *(const float4*)(Ov + (size_t)z * ZS +
                                    (size_t)(y0 + ur) * YS + (x0 + ugp * 4));
        stageA(z + 3);
        eplane(z + 1);
        __syncthreads();
        {
            const float4* e0 = &Es[(z + 8) % 3][0][0];
            const float4* e1 = &Es[(z + 9) % 3][0][0];
            const float4* e2 = &Es[(z + 10) % 3][0][0];
            float4* mm = &Ms[0][0];
            for (int j = tid; j < EJOBS; j += 256)
                mm[j] = max4(max4(e0[j], e1[j]), e2[j]);
        }
        __syncthreads();
        if (tid < UJOBS) {
            int g = ugp + 1;
            float4 d = NINF4;
#pragma unroll
            for (int dy = 0; dy < 3; ++dy) {
                float a  = Ms[ur + dy][g - 1].w;
                float4 b = Ms[ur + dy][g];
                float cx = Ms[ur + dy][g + 1].x;
                d = max4(d, win3max(a, b, cx));
            }
            float4 av = As[(z + 8) & 3][ur + 2][g];
            float4 delta = make_float4(fmaxf(av.x - d.x, 0.0f),
                                       fmaxf(av.y - d.y, 0.0f),
                                       fmaxf(av.z - d.z, 0.0f),
                                       fmaxf(av.w - d.w, 0.0f));
            size_t gi = (size_t)z * ZS + (size_t)(y0 + ur) * YS + (x0 + ugp * 4);
            float4 s = h4_to_f4(*(const H4u*)(Sv + gi));
            s.x += fmaxf(delta.x - s.x * delta.x, 0.0f);
            s.y += fmaxf(delta.y - s.y * delta.y, 0.0f);
            s.z += fmaxf(delta.z - s.z * delta.z, 0.0f);
            s.w += fmaxf(delta.w - s.w * delta.w, 0.0f);
            afd += (double)(s.x * oCur.x + s.y * oCur.y +
                            s.z * oCur.z + s.w * oCur.w);
            afs += (double)(s.x + s.y + s.z + s.w);
        }
        __syncthreads();
    }

#pragma unroll
    for (int off = 32; off > 0; off >>= 1) {
        afd += __shfl_down(afd, off, 64);
        afs += __shfl_down(afs, off, 64);
    }
    int lane = tid & 63, wid = tid >> 6;
    if (lane == 0) { sred[wid * 2] = afd; sred[wid * 2 + 1] = afs; }
    __syncthreads();
    if (tid == 0) {
        double fd = sred[0] + sred[2] + sred[4] + sred[6];
        double fs = sred[1] + sred[3] + sred[5] + sred[7];
        if (v < 2) { atomicAdd(&sums[0], fd); atomicAdd(&sums[1], fs); }
        else       { atomicAdd(&sums[2], fd); atomicAdd(&sums[3], fs); }
    }
}

__global__ void final_kernel(const double* __restrict__ sums,
                             float* __restrict__ out) {
    if (threadIdx.x == 0 && blockIdx.x == 0) {
        const double SM = 1e-5;
        double tprec = (sums[0] + SM) / (sums[1] + SM);
        double tsens = (sums[2] + SM) / (sums[3] + SM);
        double cl = 2.0 * tprec * tsens / (tprec + tsens + SM);
        out[0] = (float)(1.0 - cl);
    }
}

extern "C" void kernel_launch(void* const* d_in, const int* in_sizes, int n_in,
                              void* d_out, int out_size, void* d_ws, size_t ws_size,
                              hipStream_t stream) {
    const float* pred = (const float*)d_in[0];
    const float* target = (const float*)d_in[1];
    float* out = (float*)d_out;

    _Float16* H0 = (_Float16*)d_ws;
    _Float16* H1 = H0 + NTOT;
    _Float16* skel = H1 + NTOT;
    double* sums = (double*)(skel + NTOT);

    hipMemsetAsync(sums, 0, 4 * sizeof(double), stream);

    dim3 dgrid(NX / TX, NY / TY2, NV * 6);   /* 4 x 16 x 24 = 1536 = 6/CU */
    dim3 fgrid(NX / TX, NY / TY, NV * 4);    /* 4 x 12 x 16 = 768 = 3/CU */

    /* rounds 0,1: FIRST (reads pred/target channels directly, no skel read) */
    fused2_kernel<true><<<dgrid, 256, 0, stream>>>(pred, target, H0, H0, skel);
    /* rounds 2..49: 24 double launches on fp16 ping-pong */
    _Float16* A = H0;
    _Float16* B = H1;
    for (int j = 0; j < 24; ++j) {
        fused2_kernel<false><<<dgrid, 256, 0, stream>>>(pred, target, A, B, skel);
        _Float16* t = A; A = B; B = t;
    }
    /* round 50: single-round + fused global reduction */
    fused_last_kernel<<<fgrid, 256, 0, stream>>>(A, pred, target, skel, sums);

    final_kernel<<<1, 64, 0, stream>>>(sums, out);
}

// Round 11
// 1705.016 us; speedup vs baseline: 1.1140x; 1.1140x over previous
//
#include <hip/hip_runtime.h>
#include <math.h>

#define NX 192
#define NY 192
#define NZ 96
#define NV 4
#define VOL (NZ * NY * NX)      /* 3,538,944 */
#define NTOT (NV * VOL)         /* 14,155,776 */
#define YS NX
#define ZS (NY * NX)

/* ---- single-round (LAST) kernel geometry — round-3 verified ---- */
#define TX 48
#define TY 16
#define ZCH 24
#define NG 14
#define AROWS (TY + 4)
#define EROWS (TY + 2)
#define AJOBS (AROWS * NG)
#define EJOBS (EROWS * NG)
#define UJOBS (TY * (TX / 4))

/* ---- double-round kernel geometry (fp16 LDS + reg z-history) ---- */
#define TY2 12
#define ZCH2 16                  /* 6 z-chunks -> grid 1536 = 6 blocks/CU */
#define R2A 18                   /* A rows: halo 3 */

#define SLOT5(x) (((x) + 100) % 5)
#define SLOT3(x) (((x) + 99) % 3)
#define SLOT2(x) (((x) + 100) % 2)

#define HINF  0x7C00u
#define HNINF 0xFC00u

typedef _Float16 h2v __attribute__((ext_vector_type(2)));

struct __align__(8) H4u { unsigned lo, hi; };   /* 4 fp16: e0(low16 of lo)..e3 */

__device__ __forceinline__ h2v h2_of(unsigned u) { return __builtin_bit_cast(h2v, u); }
__device__ __forceinline__ unsigned u_of(h2v h) { return __builtin_bit_cast(unsigned, h); }

__device__ __forceinline__ H4u h4min(H4u a, H4u b) {
    H4u r;
    r.lo = u_of(__builtin_elementwise_min(h2_of(a.lo), h2_of(b.lo)));
    r.hi = u_of(__builtin_elementwise_min(h2_of(a.hi), h2_of(b.hi)));
    return r;
}
__device__ __forceinline__ H4u h4max(H4u a, H4u b) {
    H4u r;
    r.lo = u_of(__builtin_elementwise_max(h2_of(a.lo), h2_of(b.lo)));
    r.hi = u_of(__builtin_elementwise_max(h2_of(a.hi), h2_of(b.hi)));
    return r;
}
/* [p, e0, e1, e2] : left-shift-in previous element */
__device__ __forceinline__ H4u shl1(H4u c, unsigned p16) {
    H4u r;
    r.lo = (c.lo << 16) | (p16 & 0xFFFFu);
    r.hi = (c.hi << 16) | (c.lo >> 16);
    return r;
}
/* [e1, e2, e3, n] : right-shift-in next element */
__device__ __forceinline__ H4u shr1(H4u c, unsigned n16) {
    H4u r;
    r.lo = (c.lo >> 16) | (c.hi << 16);
    r.hi = (c.hi >> 16) | ((n16 & 0xFFFFu) << 16);
    return r;
}
__device__ __forceinline__ H4u f4_to_h4(float4 f) {
    h2v a, b;
    a[0] = (_Float16)f.x; a[1] = (_Float16)f.y;
    b[0] = (_Float16)f.z; b[1] = (_Float16)f.w;
    H4u r; r.lo = u_of(a); r.hi = u_of(b); return r;
}
__device__ __forceinline__ float4 h4_to_f4(H4u h) {
    h2v a = h2_of(h.lo), b = h2_of(h.hi);
    return make_float4((float)a[0], (float)a[1], (float)b[0], (float)b[1]);
}

__device__ __forceinline__ float4 min4(float4 a, float4 b) {
    return make_float4(fminf(a.x, b.x), fminf(a.y, b.y),
                       fminf(a.z, b.z), fminf(a.w, b.w));
}
__device__ __forceinline__ float4 max4(float4 a, float4 b) {
    return make_float4(fmaxf(a.x, b.x), fmaxf(a.y, b.y),
                       fmaxf(a.z, b.z), fmaxf(a.w, b.w));
}
__device__ __forceinline__ float4 win3max(float a, float4 b, float c) {
    return make_float4(fmaxf(fmaxf(a, b.x), b.y),
                       fmaxf(fmaxf(b.x, b.y), b.z),
                       fmaxf(fmaxf(b.y, b.z), b.w),
                       fmaxf(fmaxf(b.z, b.w), c));
}

// ---------------- double-round kernel: reg z-history version ---------------
// Thread (lr,c) owns absolute row y = y0-2+lr (E1 row lr). Rolling register
// histories: e1 (E1 at z-3..z), e2 (E2 at z-2,z-1), zm1/zm2 (zmax planes).
// LDS: A ring (rows via sr/sg), E1-center ring (y+-1 for E2), ZM1/ZM2 rings
// (y+-1 for the dilates). One barrier per step; all ring slots disjoint.
template<bool FIRST>
__global__ __launch_bounds__(256, 6) void fused2_kernel(
    const float* __restrict__ pred, const float* __restrict__ target,
    const _Float16* __restrict__ Ain, _Float16* __restrict__ Eout,
    _Float16* __restrict__ skel)
{
    __shared__ H4u As[5][R2A][NG];
    __shared__ H4u E1c[3][16][NG];
    __shared__ H4u ZM1[2][16][NG];
    __shared__ H4u ZM2[2][16][NG];

    const int tid = threadIdx.x;
    const int lr  = tid >> 4;               /* row lane 0..15 */
    const int c   = tid & 15;               /* col group 0..15 (0..13 real) */
    const int cc  = (c < 14) ? c : 13;
    const int sr  = tid / 14;               /* stage row 0..18 (252 active) */
    const int sg  = tid - sr * 14;

    const int x0 = blockIdx.x * TX;
    const int y0 = blockIdx.y * TY2;
    const int v  = blockIdx.z / 6;
    const int ch = blockIdx.z % 6;
    const int z0 = ch * ZCH2;
    const int z1 = z0 + ZCH2;

    const float* Af = nullptr;
    const _Float16* Ah = nullptr;
    if (FIRST) Af = ((v < 2) ? pred : target) + (size_t)((v & 1) * 2 + 1) * VOL;
    else       Ah = Ain + (size_t)v * VOL;
    _Float16* Ev = Eout + (size_t)v * VOL;
    _Float16* Sv = skel + (size_t)v * VOL;

    const H4u HP4 = { 0x7C007C00u, 0x7C007C00u };   /* +inf x4 */
    const H4u HN4 = { 0xFC00FC00u, 0xFC00FC00u };   /* -inf x4 */
    const float4 ZERO4 = make_float4(0.f, 0.f, 0.f, 0.f);

    const bool xlo = (x0 == 0);
    const bool xhi = (x0 + TX == NX);

    const int  gys  = y0 - 3 + sr;
    const int  gxs  = x0 - 4 + 4 * sg;
    const bool stIn = (sr < R2A) && (gys >= 0) && (gys < NY) &&
                      (gxs >= 0) && (gxs < NX);

    const int  gx   = x0 - 4 + 4 * c;
    const bool gxin = (c < 14) && (gx >= 0) && (gx < NX);
    const int  gyo  = y0 - 2 + lr;          /* own absolute row */
    const bool yIn  = (gyo >= 0) && (gyo < NY);
    const bool uAct = (lr >= 2 && lr <= 13 && c >= 1 && c <= 12);
    const int  rdn  = (lr > 0) ? lr - 1 : 0;
    const int  rup  = (lr < 15) ? lr + 1 : 15;

    auto stageLoad = [&](int za) -> H4u {
        H4u val = HP4;
        if (stIn && za >= 0 && za < NZ) {
            if (FIRST)
                val = f4_to_h4(*(const float4*)(Af + (size_t)za * ZS + gys * YS + gxs));
            else
                val = *(const H4u*)(Ah + (size_t)za * ZS + gys * YS + gxs);
        }
        return val;
    };
    auto stageWrite = [&](int za, H4u val) {
        if (sr < R2A) As[SLOT5(za)][sr][sg] = val;
    };

    /* E1(zp) at own row; writes center to E1c ring; returns value */
    auto e1compute = [&](int zp) -> H4u {
        if (zp >= NZ) return HP4;
        const int s_c = SLOT5(zp), s_m = SLOT5(zp - 1), s_p = SLOT5(zp + 1);
        const bool hp = (zp + 1 < NZ);
        const int ar = lr + 1;
        H4u cen = As[s_c][ar][cc];
        H4u ylo = As[s_c][ar - 1][cc];
        H4u yhi = As[s_c][ar + 1][cc];
        H4u zlo = As[s_m][ar][cc];
        H4u zhi = hp ? As[s_p][ar][cc] : HP4;
        unsigned lw = __shfl_up(cen.hi, 1) >> 16;
        unsigned rx = __shfl_down(cen.lo, 1) & 0xFFFFu;
        if (c == 0) lw = HINF;
        H4u m = h4min(cen, shl1(cen, lw));
        m = h4min(m, shr1(cen, rx));
        m = h4min(m, h4min(ylo, yhi));
        m = h4min(m, h4min(zlo, zhi));
        if (zp < 0 || !yIn || !gxin) m = HP4;
        if (c < 14) E1c[SLOT3(zp)][lr][c] = m;
        return m;
    };

    // ---- prologue: A(z0-3..z0+2), E1(z0-2..z0) ----
    stageWrite(z0 - 3, stageLoad(z0 - 3));
    stageWrite(z0 - 2, stageLoad(z0 - 2));
    stageWrite(z0 - 1, stageLoad(z0 - 1));
    stageWrite(z0,     stageLoad(z0));
    stageWrite(z0 + 1, stageLoad(z0 + 1));
    __syncthreads();
    H4u e1m2 = e1compute(z0 - 2);
    H4u e1m1 = e1compute(z0 - 1);
    __syncthreads();
    stageWrite(z0 + 2, stageLoad(z0 + 2));
    H4u e1c = e1compute(z0);
    __syncthreads();

    H4u e1m3 = HP4;
    H4u e2c = HN4, e2m1 = HN4;
    H4u zm1_prev = HN4, zm2_prev = HN4;
    float4 skA = ZERO4, sq1 = ZERO4, sq2 = ZERO4;

    // ---- main loop: one barrier per step ----
    for (int z = z0; z <= z1 + 2; ++z) {
        const bool doStage = (z <= z1 - 1);
        H4u stv = doStage ? stageLoad(z + 3) : HP4;
        float4 skN = ZERO4;
        if (!FIRST && z < z1 && uAct)
            skN = h4_to_f4(*(const H4u*)(Sv + (size_t)z * ZS + gyo * YS + gx));

        /* E1(z+1) */
        H4u e1new = (z + 1 <= z1 + 1) ? e1compute(z + 1) : HP4;

        /* zmax1(z) = dilate-z of E1 at own cell */
        H4u zm1w;
        {
            H4u t0 = (z >= 1) ? e1m1 : HN4;
            H4u t2 = (z + 1 < NZ) ? e1new : HN4;
            zm1w = h4max(t0, h4max(e1c, t2));
            if (!yIn || !gxin) zm1w = HN4;
            if (c < 14) ZM1[SLOT2(z)][lr][c] = zm1w;
        }

        /* E2(p=z-1) at own cell + global E write */
        const int p = z - 1;
        H4u e2new = HN4;
        if (p >= 0 && p <= z1 && p < NZ) {
            H4u cen = e1m1;                 /* E1(p) center */
            H4u zlo = e1m2;                 /* E1(p-1), erode pad ok */
            H4u zhi = e1c;                  /* E1(p+1), HP4 if never computed */
            H4u ylo = E1c[SLOT3(p)][rdn][cc];
            H4u yhi = E1c[SLOT3(p)][rup][cc];
            unsigned lwE = __shfl_up(cen.hi, 1) >> 16;
            unsigned rxE = __shfl_down(cen.lo, 1) & 0xFFFFu;
            if (c == 0) lwE = HINF;
            H4u m2 = h4min(cen, shl1(cen, lwE));
            m2 = h4min(m2, shr1(cen, rxE));
            m2 = h4min(m2, h4min(ylo, yhi));
            m2 = h4min(m2, h4min(zlo, zhi));
            if (yIn && gxin) {
                e2new = m2;
                if (p >= z0 && p < z1 && lr >= 2 && lr <= 13 && c >= 1 && c <= 12)
                    *(H4u*)(Ev + (size_t)p * ZS + gyo * YS + gx) = m2;
            }
        }

        /* zmax2(z-2) = dilate-z of E2 at own cell (all HN4-padded) */
        H4u zm2w = h4max(e2m1, h4max(e2c, e2new));
        if (c < 14) ZM2[SLOT2(z - 2)][lr][c] = zm2w;

        /* upd1(p = z-1): delta vs dilate(E1), accumulate into reg chain */
        float4 spnew = ZERO4;
        if (p >= z0 && p < z1) {
            H4u vm = h4max(ZM1[SLOT2(p)][rdn][cc],
                     h4max(zm1_prev, ZM1[SLOT2(p)][rup][cc]));
            unsigned lw = __shfl_up(vm.hi, 1) >> 16;
            unsigned rx = __shfl_down(vm.lo, 1) & 0xFFFFu;
            if (xlo && c == 1)  lw = HNINF;
            if (xhi && c == 12) rx = HNINF;
            if (uAct) {
                H4u dilh = h4max(h4max(shl1(vm, lw), vm), shr1(vm, rx));
                float4 dil = h4_to_f4(dilh);
                float4 a = h4_to_f4(As[SLOT5(p)][lr + 1][cc]);
                float4 s = skA;
                float dd;
                dd = fmaxf(a.x - dil.x, 0.f); s.x += fmaxf(dd - s.x * dd, 0.f);
                dd = fmaxf(a.y - dil.y, 0.f); s.y += fmaxf(dd - s.y * dd, 0.f);
                dd = fmaxf(a.z - dil.z, 0.f); s.z += fmaxf(dd - s.z * dd, 0.f);
                dd = fmaxf(a.w - dil.w, 0.f); s.w += fmaxf(dd - s.w * dd, 0.f);
                spnew = s;
            }
        }

        /* upd2(q = z-3): delta vs dilate(E2), write skel */
        const int q = z - 3;
        if (q >= z0 && q < z1) {
            H4u vm2 = h4max(ZM2[SLOT2(q)][rdn][cc],
                      h4max(zm2_prev, ZM2[SLOT2(q)][rup][cc]));
            unsigned lw = __shfl_up(vm2.hi, 1) >> 16;
            unsigned rx = __shfl_down(vm2.lo, 1) & 0xFFFFu;
            if (xlo && c == 1)  lw = HNINF;
            if (xhi && c == 12) rx = HNINF;
            if (uAct) {
                H4u dilh = h4max(h4max(shl1(vm2, lw), vm2), shr1(vm2, rx));
                float4 dil = h4_to_f4(dilh);
                float4 a = h4_to_f4(e1m3);   /* E1(q) own center */
                float4 s = sq2;
                float dd;
                dd = fmaxf(a.x - dil.x, 0.f); s.x += fmaxf(dd - s.x * dd, 0.f);
                dd = fmaxf(a.y - dil.y, 0.f); s.y += fmaxf(dd - s.y * dd, 0.f);
                dd = fmaxf(a.z - dil.z, 0.f); s.z += fmaxf(dd - s.z * dd, 0.f);
                dd = fmaxf(a.w - dil.w, 0.f); s.w += fmaxf(dd - s.w * dd, 0.f);
                *(H4u*)(Sv + (size_t)q * ZS + gyo * YS + gx) = f4_to_h4(s);
            }
        }

        /* commit staged A plane */
        if (doStage) stageWrite(z + 3, stv);

        __syncthreads();
        /* register rotations */
        e1m3 = e1m2; e1m2 = e1m1; e1m1 = e1c; e1c = e1new;
        e2m1 = e2c; e2c = e2new;
        zm1_prev = zm1w; zm2_prev = zm2w;
        sq2 = sq1; sq1 = spnew; skA = skN;
    }
}

// ---------------- LAST single-round kernel (round 50 + fused reduction) -----
// Round-10 verified verbatim: A + skel read fp16, no skel store, fused sums.
__global__ __launch_bounds__(256, 3) void fused_last_kernel(
    const _Float16* __restrict__ Ain,
    const float* __restrict__ pred, const float* __restrict__ target,
    const _Float16* __restrict__ skel, double* __restrict__ sums)
{
    __shared__ float4 As[4][AROWS][NG];
    __shared__ float4 Es[3][EROWS][NG];
    __shared__ float4 Ms[EROWS][NG];
    __shared__ double sred[8];

    const int tid = threadIdx.x;
    const int x0 = blockIdx.x * TX;
    const int y0 = blockIdx.y * TY;
    const int v  = blockIdx.z >> 2;
    const int z0 = (blockIdx.z & 3) * ZCH;
    const int z1 = z0 + ZCH;

    const _Float16* Av = Ain + (size_t)v * VOL;
    const _Float16* Sv = skel + (size_t)v * VOL;
    const float* Ov = ((v < 2) ? target : pred) + (size_t)((v & 1) * 2 + 1) * VOL;

    const float4 PINF4 = make_float4(INFINITY, INFINITY, INFINITY, INFINITY);
    const float4 NINF4 = make_float4(-INFINITY, -INFINITY, -INFINITY, -INFINITY);
    const float4 ZERO4 = make_float4(0.f, 0.f, 0.f, 0.f);

    const int ur  = tid / (TX / 4);
    const int ugp = tid - ur * (TX / 4);

    auto stageA = [&](int z) {
        int slot = (z + 8) & 3;
        float4* dst = &As[slot][0][0];
        if (z < 0 || z >= NZ) {
            for (int j = tid; j < AJOBS; j += 256) dst[j] = PINF4;
        } else {
            const _Float16* P = Av + (size_t)z * ZS;
            for (int j = tid; j < AJOBS; j += 256) {
                int r = j / NG, g = j - r * NG;
                int gy = y0 - 2 + r;
                int gx0 = x0 - 4 + 4 * g;
                float4 val = PINF4;
                if (gy >= 0 && gy < NY && gx0 >= 0 && gx0 < NX)
                    val = h4_to_f4(*(const H4u*)(P + gy * YS + gx0));
                dst[j] = val;
            }
        }
    };

    auto eplane = [&](int z) {
        int es = (z + 9) % 3;
        float4* dst = &Es[es][0][0];
        if (z < 0 || z >= NZ) {
            for (int j = tid; j < EJOBS; j += 256) dst[j] = NINF4;
            return;
        }
        const int sc = (z + 8) & 3;
        const int sm = (z + 7) & 3;
        const int sp = (z + 9) & 3;
        for (int j = tid; j < EJOBS; j += 256) {
            int r = j / NG, g = j - r * NG;
            float4 c  = As[sc][r + 1][g];
            float4 yl = As[sc][r][g];
            float4 yh = As[sc][r + 2][g];
            float4 zl = As[sm][r + 1][g];
            float4 zh = As[sp][r + 1][g];
            float pw = (g > 0)      ? As[sc][r + 1][g - 1].w : INFINITY;
            float nx = (g < NG - 1) ? As[sc][r + 1][g + 1].x : INFINITY;
            float4 xl = make_float4(pw, c.x, c.y, c.z);
            float4 xr = make_float4(c.y, c.z, c.w, nx);
            float4 m = min4(c, xl);
            m = min4(m, xr);
            m = min4(m, yl);
            m = min4(m, yh);
            m = min4(m, zl);
            m = min4(m, zh);
            int gy = y0 - 1 + r;
            int gx0 = x0 - 4 + 4 * g;
            if (gy < 0 || gy >= NY || gx0 < 0 || gx0 >= NX) m = NINF4;
            dst[j] = m;
        }
    };

    stageA(z0 - 2); stageA(z0 - 1); stageA(z0); stageA(z0 + 1);
    __syncthreads();
    eplane(z0 - 1);
    eplane(z0);
    __syncthreads();
    stageA(z0 + 2);
    __syncthreads();

    double afd = 0.0, afs = 0.0;

    for (int z = z0; z < z1; ++z) {
        float4 oCur = ZERO4;
        if (tid < UJOBS)
            oCur = *(const float4*)(Ov + (size_t)z * ZS +
                                    (size_t)(y0 + ur) * YS + (x0 + ugp * 4));
        stageA(z + 3);
        eplane(z + 1);
        __syncthreads();
        {
            const float4* e0 = &Es[(z + 8) % 3][0][0];
            const float4* e1 = &Es[(z + 9) % 3][0][0];
            const float4* e2 = &Es[(z + 10) % 3][0][0];
            float4* mm = &Ms[0][0];
            for (int j = tid; j < EJOBS; j += 256)
                mm[j] = max4(max4(e0[j], e1[j]), e2[j]);
        }
        __syncthreads();
        if (tid < UJOBS) {
            int g = ugp + 1;
            float4 d = NINF4;
#pragma unroll
            for (int dy = 0; dy < 3; ++dy) {
                float a  = Ms[ur + dy][g - 1].w;
                float4 b = Ms[ur + dy][g];
                float cx = Ms[ur + dy][g + 1].x;
                d = max4(d, win3max(a, b, cx));
            }
            float4 av = As[(z + 8) & 3][ur + 2][g];
            float4 delta = make_float4(fmaxf(av.x - d.x, 0.0f),
                                       fmaxf(av.y - d.y, 0.0f),
                                       fmaxf(av.z - d.z, 0.0f),
                                       fmaxf(av.w - d.w, 0.0f));
            size_t gi = (size_t)z * ZS + (size_t)(y0 + ur) * YS + (x0 + ugp * 4);
            float4 s = h4_to_f4(*(const H4u*)(Sv + gi));
            s.x += fmaxf(delta.x - s.x * delta.x, 0.0f);
            s.y += fmaxf(delta.y - s.y * delta.y, 0.0f);
            s.z += fmaxf(delta.z - s.z * delta.z, 0.0f);
            s.w += fmaxf(delta.w - s.w * delta.w, 0.0f);
            afd += (double)(s.x * oCur.x + s.y * oCur.y +
                            s.z * oCur.z + s.w * oCur.w);
            afs += (double)(s.x + s.y + s.z + s.w);
        }
        __syncthreads();
    }

#pragma unroll
    for (int off = 32; off > 0; off >>= 1) {
        afd += __shfl_down(afd, off, 64);
        afs += __shfl_down(afs, off, 64);
    }
    int lane = tid & 63, wid = tid >> 6;
    if (lane == 0) { sred[wid * 2] = afd; sred[wid * 2 + 1] = afs; }
    __syncthreads();
    if (tid == 0) {
        double fd = sred[0] + sred[2] + sred[4] + sred[6];
        double fs = sred[1] + sred[3] + sred[5] + sred[7];
        if (v < 2) { atomicAdd(&sums[0], fd); atomicAdd(&sums[1], fs); }
        else       { atomicAdd(&sums[2], fd); atomicAdd(&sums[3], fs); }
    }
}

__global__ void final_kernel(const double* __restrict__ sums,
                             float* __restrict__ out) {
    if (threadIdx.x == 0 && blockIdx.x == 0) {
        const double SM = 1e-5;
        double tprec = (sums[0] + SM) / (sums[1] + SM);
        double tsens = (sums[2] + SM) / (sums[3] + SM);
        double cl = 2.0 * tprec * tsens / (tprec + tsens + SM);
        out[0] = (float)(1.0 - cl);
    }
}

extern "C" void kernel_launch(void* const* d_in, const int* in_sizes, int n_in,
                              void* d_out, int out_size, void* d_ws, size_t ws_size,
                              hipStream_t stream) {
    const float* pred = (const float*)d_in[0];
    const float* target = (const float*)d_in[1];
    float* out = (float*)d_out;

    _Float16* H0 = (_Float16*)d_ws;
    _Float16* H1 = H0 + NTOT;
    _Float16* skel = H1 + NTOT;
    double* sums = (double*)(skel + NTOT);

    hipMemsetAsync(sums, 0, 4 * sizeof(double), stream);

    dim3 dgrid(NX / TX, NY / TY2, NV * 6);   /* 4 x 16 x 24 = 1536 = 6/CU */
    dim3 fgrid(NX / TX, NY / TY, NV * 4);    /* 4 x 12 x 16 = 768 = 3/CU */

    /* rounds 0,1: FIRST (reads pred/target channels directly, no skel read) */
    fused2_kernel<true><<<dgrid, 256, 0, stream>>>(pred, target, H0, H0, skel);
    /* rounds 2..49: 24 double launches on fp16 ping-pong */
    _Float16* A = H0;
    _Float16* B = H1;
    for (int j = 0; j < 24; ++j) {
        fused2_kernel<false><<<dgrid, 256, 0, stream>>>(pred, target, A, B, skel);
        _Float16* t = A; A = B; B = t;
    }
    /* round 50: single-round + fused global reduction */
    fused_last_kernel<<<fgrid, 256, 0, stream>>>(A, pred, target, skel, sums);

    final_kernel<<<1, 64, 0, stream>>>(sums, out);
}

// Round 12
// 1444.197 us; speedup vs baseline: 1.3152x; 1.1806x over previous
//
#include <hip/hip_runtime.h>
#include <math.h>

#define NX 192
#define NY 192
#define NZ 96
#define NV 4
#define VOL (NZ * NY * NX)      /* 3,538,944 */
#define NTOT (NV * VOL)         /* 14,155,776 */
#define YS NX
#define ZS (NY * NX)

#define TX 48
#define TY2 12
#define ZCH2 16                  /* 6 z-chunks -> grid 1536 = 6 blocks/CU */
#define NG 14
#define R2A 18

#define SLOT4(x) (((x) + 100) % 4)
#define SLOT3(x) (((x) + 99) % 3)
#define SLOT2(x) (((x) + 100) % 2)

#define HINF  0x7C00u
#define HNINF 0xFC00u

typedef _Float16 h2v __attribute__((ext_vector_type(2)));

struct __align__(8) H4u { unsigned lo, hi; };

__device__ __forceinline__ h2v h2_of(unsigned u) { return __builtin_bit_cast(h2v, u); }
__device__ __forceinline__ unsigned u_of(h2v h) { return __builtin_bit_cast(unsigned, h); }

__device__ __forceinline__ H4u h4min(H4u a, H4u b) {
    H4u r;
    r.lo = u_of(__builtin_elementwise_min(h2_of(a.lo), h2_of(b.lo)));
    r.hi = u_of(__builtin_elementwise_min(h2_of(a.hi), h2_of(b.hi)));
    return r;
}
__device__ __forceinline__ H4u h4max(H4u a, H4u b) {
    H4u r;
    r.lo = u_of(__builtin_elementwise_max(h2_of(a.lo), h2_of(b.lo)));
    r.hi = u_of(__builtin_elementwise_max(h2_of(a.hi), h2_of(b.hi)));
    return r;
}
__device__ __forceinline__ H4u h4add(H4u a, H4u b) {
    H4u r;
    r.lo = u_of(h2_of(a.lo) + h2_of(b.lo));
    r.hi = u_of(h2_of(a.hi) + h2_of(b.hi));
    return r;
}
__device__ __forceinline__ H4u h4sub(H4u a, H4u b) {
    H4u r;
    r.lo = u_of(h2_of(a.lo) - h2_of(b.lo));
    r.hi = u_of(h2_of(a.hi) - h2_of(b.hi));
    return r;
}
__device__ __forceinline__ H4u h4mul(H4u a, H4u b) {
    H4u r;
    r.lo = u_of(h2_of(a.lo) * h2_of(b.lo));
    r.hi = u_of(h2_of(a.hi) * h2_of(b.hi));
    return r;
}
__device__ __forceinline__ H4u h4skel(H4u s, H4u a, H4u dil) {
    const H4u HZ4 = { 0u, 0u };
    const H4u HONE = { 0x3C003C00u, 0x3C003C00u };
    H4u dd = h4max(h4sub(a, dil), HZ4);
    H4u t = h4mul(dd, h4sub(HONE, s));
    return h4add(s, h4max(t, HZ4));
}
__device__ __forceinline__ H4u shl1(H4u c, unsigned p16) {
    H4u r;
    r.lo = (c.lo << 16) | (p16 & 0xFFFFu);
    r.hi = (c.hi << 16) | (c.lo >> 16);
    return r;
}
__device__ __forceinline__ H4u shr1(H4u c, unsigned n16) {
    H4u r;
    r.lo = (c.lo >> 16) | (c.hi << 16);
    r.hi = (c.hi >> 16) | ((n16 & 0xFFFFu) << 16);
    return r;
}
__device__ __forceinline__ H4u f4_to_h4(float4 f) {
    h2v a, b;
    a[0] = (_Float16)f.x; a[1] = (_Float16)f.y;
    b[0] = (_Float16)f.z; b[1] = (_Float16)f.w;
    H4u r; r.lo = u_of(a); r.hi = u_of(b); return r;
}
__device__ __forceinline__ float4 h4_to_f4(H4u h) {
    h2v a = h2_of(h.lo), b = h2_of(h.hi);
    return make_float4((float)a[0], (float)a[1], (float)b[0], (float)b[1]);
}

template<bool FIRST>
__global__ __launch_bounds__(256, 6) void fused2_kernel(
    const float* __restrict__ pred, const float* __restrict__ target,
    const _Float16* __restrict__ Ain, _Float16* __restrict__ Eout,
    _Float16* __restrict__ skel)
{
    __shared__ H4u As[4][R2A][NG];
    __shared__ H4u E1c[3][16][NG];
    __shared__ H4u ZM1[2][16][NG];
    __shared__ H4u ZM2[2][16][NG];

    const int tid = threadIdx.x;
    const int lr  = tid >> 4;
    const int c   = tid & 15;
    const int cc  = (c < 14) ? c : 13;
    const int sr  = tid / 14;
    const int sg  = tid - sr * 14;

    const int x0 = blockIdx.x * TX;
    const int y0 = blockIdx.y * TY2;
    const int v  = blockIdx.z / 6;
    const int ch = blockIdx.z % 6;
    const int z0 = ch * ZCH2;
    const int z1 = z0 + ZCH2;

    const float* Af = nullptr;
    const _Float16* Ah = nullptr;
    if (FIRST) Af = ((v < 2) ? pred : target) + (size_t)((v & 1) * 2 + 1) * VOL;
    else       Ah = Ain + (size_t)v * VOL;
    _Float16* Ev = Eout + (size_t)v * VOL;
    _Float16* Sv = skel + (size_t)v * VOL;

    const H4u HP4 = { 0x7C007C00u, 0x7C007C00u };
    const H4u HN4 = { 0xFC00FC00u, 0xFC00FC00u };
    const H4u HZ4 = { 0u, 0u };

    const bool xlo = (x0 == 0);
    const bool xhi = (x0 + TX == NX);

    const int  gys  = y0 - 3 + sr;
    const int  gxs  = x0 - 4 + 4 * sg;
    const bool stIn = (sr < R2A) && (gys >= 0) && (gys < NY) &&
                      (gxs >= 0) && (gxs < NX);

    const int  gx   = x0 - 4 + 4 * c;
    const bool gxin = (c < 14) && (gx >= 0) && (gx < NX);
    const int  gyo  = y0 - 2 + lr;
    const bool yIn  = (gyo >= 0) && (gyo < NY);
    const bool uAct = (lr >= 2 && lr <= 13 && c >= 1 && c <= 12);
    const int  rdn  = (lr > 0) ? lr - 1 : 0;
    const int  rup  = (lr < 15) ? lr + 1 : 15;

    auto stageLoad = [&](int za) -> H4u {
        H4u val = HP4;
        if (stIn && za >= 0 && za < NZ) {
            if (FIRST)
                val = f4_to_h4(*(const float4*)(Af + (size_t)za * ZS + gys * YS + gxs));
            else
                val = *(const H4u*)(Ah + (size_t)za * ZS + gys * YS + gxs);
        }
        return val;
    };
    auto stageWrite = [&](int za, H4u val) {
        if (sr < R2A) As[SLOT4(za)][sr][sg] = val;
    };

    auto e1compute = [&](int zp, H4u& cenOut) -> H4u {
        if (zp >= NZ) { cenOut = HP4; return HP4; }
        const int s_c = SLOT4(zp), s_m = SLOT4(zp - 1), s_p = SLOT4(zp + 1);
        const bool hp = (zp + 1 < NZ);
        const int ar = lr + 1;
        H4u cen = As[s_c][ar][cc];
        H4u ylo = As[s_c][ar - 1][cc];
        H4u yhi = As[s_c][ar + 1][cc];
        H4u zlo = As[s_m][ar][cc];
        H4u zhi = hp ? As[s_p][ar][cc] : HP4;
        cenOut = cen;
        unsigned lw = __shfl_up(cen.hi, 1) >> 16;
        unsigned rx = __shfl_down(cen.lo, 1) & 0xFFFFu;
        if (c == 0) lw = HINF;
        H4u m = h4min(cen, shl1(cen, lw));
        m = h4min(m, shr1(cen, rx));
        m = h4min(m, h4min(ylo, yhi));
        m = h4min(m, h4min(zlo, zhi));
        if (zp < 0 || !yIn || !gxin) m = HP4;
        if (c < 14) E1c[SLOT3(zp)][lr][c] = m;
        return m;
    };

    stageWrite(z0 - 3, stageLoad(z0 - 3));
    stageWrite(z0 - 2, stageLoad(z0 - 2));
    stageWrite(z0 - 1, stageLoad(z0 - 1));
    stageWrite(z0,     stageLoad(z0));
    __syncthreads();
    H4u aT, a1, a2 = HP4;
    H4u e1m2 = e1compute(z0 - 2, aT);
    H4u e1m1 = e1compute(z0 - 1, aT);
    __syncthreads();
    stageWrite(z0 + 1, stageLoad(z0 + 1));
    __syncthreads();
    H4u e1c = e1compute(z0, a1);
    stageWrite(z0 + 2, stageLoad(z0 + 2));
    __syncthreads();

    H4u e1m3 = HP4;
    H4u e2c = HN4, e2m1 = HN4;
    H4u zm1_prev = HN4, zm2_prev = HN4;
    H4u skA = HZ4, sq1 = HZ4, sq2 = HZ4;

    for (int z = z0; z <= z1 + 2; ++z) {
        const bool doStage = (z <= z1 - 1);
        H4u stv = doStage ? stageLoad(z + 3) : HP4;
        H4u skN = HZ4;
        if (!FIRST && z < z1 && uAct)
            skN = *(const H4u*)(Sv + (size_t)z * ZS + gyo * YS + gx);

        H4u aC = HP4;
        H4u e1new = (z <= z1) ? e1compute(z + 1, aC) : HP4;

        H4u zm1w;
        {
            H4u t0 = (z >= 1) ? e1m1 : HN4;
            H4u t2 = (z + 1 < NZ) ? e1new : HN4;
            zm1w = h4max(t0, h4max(e1c, t2));
            if (!yIn || !gxin) zm1w = HN4;
            if (c < 14) ZM1[SLOT2(z)][lr][c] = zm1w;
        }

        const int p = z - 1;
        H4u e2new = HN4;
        if (p >= 0 && p <= z1 && p < NZ) {
            H4u cen = e1m1;
            H4u zlo = e1m2;
            H4u zhi = e1c;
            H4u ylo = E1c[SLOT3(p)][rdn][cc];
            H4u yhi = E1c[SLOT3(p)][rup][cc];
            unsigned lwE = __shfl_up(cen.hi, 1) >> 16;
            unsigned rxE = __shfl_down(cen.lo, 1) & 0xFFFFu;
            if (c == 0) lwE = HINF;
            H4u m2 = h4min(cen, shl1(cen, lwE));
            m2 = h4min(m2, shr1(cen, rxE));
            m2 = h4min(m2, h4min(ylo, yhi));
            m2 = h4min(m2, h4min(zlo, zhi));
            if (yIn && gxin) {
                e2new = m2;
                if (p >= z0 && p < z1 && lr >= 2 && lr <= 13 && c >= 1 && c <= 12)
                    *(H4u*)(Ev + (size_t)p * ZS + gyo * YS + gx) = m2;
            }
        }

        H4u zm2w = h4max(e2m1, h4max(e2c, e2new));
        if (c < 14) ZM2[SLOT2(z - 2)][lr][c] = zm2w;

        H4u spnew = HZ4;
        if (p >= z0 && p < z1) {
            H4u vm = h4max(ZM1[SLOT2(p)][rdn][cc],
                     h4max(zm1_prev, ZM1[SLOT2(p)][rup][cc]));
            unsigned lw = __shfl_up(vm.hi, 1) >> 16;
            unsigned rx = __shfl_down(vm.lo, 1) & 0xFFFFu;
            if (xlo && c == 1)  lw = HNINF;
            if (xhi && c == 12) rx = HNINF;
            if (uAct) {
                H4u dilh = h4max(h4max(shl1(vm, lw), vm), shr1(vm, rx));
                spnew = h4skel(skA, a2, dilh);
            }
        }

        const int q = z - 3;
        if (q >= z0 && q < z1) {
            H4u vm2 = h4max(ZM2[SLOT2(q)][rdn][cc],
                      h4max(zm2_prev, ZM2[SLOT2(q)][rup][cc]));
            unsigned lw = __shfl_up(vm2.hi, 1) >> 16;
            unsigned rx = __shfl_down(vm2.lo, 1) & 0xFFFFu;
            if (xlo && c == 1)  lw = HNINF;
            if (xhi && c == 12) rx = HNINF;
            if (uAct) {
                H4u dilh = h4max(h4max(shl1(vm2, lw), vm2), shr1(vm2, rx));
                H4u s = h4skel(sq2, e1m3, dilh);
                *(H4u*)(Sv + (size_t)q * ZS + gyo * YS + gx) = s;
            }
        }

        if (doStage) stageWrite(z + 3, stv);

        __syncthreads();
        e1m3 = e1m2; e1m2 = e1m1; e1m1 = e1c; e1c = e1new;
        e2m1 = e2c; e2c = e2new;
        zm1_prev = zm1w; zm2_prev = zm2w;
        a2 = a1; a1 = aC;
        sq2 = sq1; sq1 = spnew; skA = skN;
    }
}

__global__ __launch_bounds__(256, 6) void last_kernel(
    const _Float16* __restrict__ Ain,
    const float* __restrict__ pred, const float* __restrict__ target,
    const _Float16* __restrict__ skel, double* __restrict__ sums)
{
    __shared__ H4u As[4][R2A][NG];
    __shared__ H4u ZM1[2][16][NG];
    __shared__ double sred[8];

    const int tid = threadIdx.x;
    const int lr  = tid >> 4;
    const int c   = tid & 15;
    const int cc  = (c < 14) ? c : 13;
    const int sr  = tid / 14;
    const int sg  = tid - sr * 14;

    const int x0 = blockIdx.x * TX;
    const int y0 = blockIdx.y * TY2;
    const int v  = blockIdx.z / 6;
    const int ch = blockIdx.z % 6;
    const int z0 = ch * ZCH2;
    const int z1 = z0 + ZCH2;

    const _Float16* Ah = Ain + (size_t)v * VOL;
    const _Float16* Sv = skel + (size_t)v * VOL;
    const float* Ov = ((v < 2) ? target : pred) + (size_t)((v & 1) * 2 + 1) * VOL;

    const H4u HP4 = { 0x7C007C00u, 0x7C007C00u };
    const H4u HN4 = { 0xFC00FC00u, 0xFC00FC00u };
    const H4u HZ4 = { 0u, 0u };
    const float4 ZERO4 = make_float4(0.f, 0.f, 0.f, 0.f);

    const bool xlo = (x0 == 0);
    const bool xhi = (x0 + TX == NX);

    const int  gys  = y0 - 3 + sr;
    const int  gxs  = x0 - 4 + 4 * sg;
    const bool stIn = (sr < R2A) && (gys >= 0) && (gys < NY) &&
                      (gxs >= 0) && (gxs < NX);

    const int  gx   = x0 - 4 + 4 * c;
    const bool gxin = (c < 14) && (gx >= 0) && (gx < NX);
    const int  gyo  = y0 - 2 + lr;
    const bool yIn  = (gyo >= 0) && (gyo < NY);
    const bool uAct = (lr >= 2 && lr <= 13 && c >= 1 && c <= 12);
    const int  rdn  = (lr > 0) ? lr - 1 : 0;
    const int  rup  = (lr < 15) ? lr + 1 : 15;

    auto stageLoad = [&](int za) -> H4u {
        H4u val = HP4;
        if (stIn && za >= 0 && za < NZ)
            val = *(const H4u*)(Ah + (size_t)za * ZS + gys * YS + gxs);
        return val;
    };
    auto stageWrite = [&](int za, H4u val) {
        if (sr < R2A) As[SLOT4(za)][sr][sg] = val;
    };

    auto e1compute = [&](int zp, H4u& cenOut) -> H4u {
        if (zp >= NZ) { cenOut = HP4; return HP4; }
        const int s_c = SLOT4(zp), s_m = SLOT4(zp - 1), s_p = SLOT4(zp + 1);
        const bool hp = (zp + 1 < NZ);
        const int ar = lr + 1;
        H4u cen = As[s_c][ar][cc];
        H4u ylo = As[s_c][ar - 1][cc];
        H4u yhi = As[s_c][ar + 1][cc];
        H4u zlo = As[s_m][ar][cc];
        H4u zhi = hp ? As[s_p][ar][cc] : HP4;
        cenOut = cen;
        unsigned lw = __shfl_up(cen.hi, 1) >> 16;
        unsigned rx = __shfl_down(cen.lo, 1) & 0xFFFFu;
        if (c == 0) lw = HINF;
        H4u m = h4min(cen, shl1(cen, lw));
        m = h4min(m, shr1(cen, rx));
        m = h4min(m, h4min(ylo, yhi));
        m = h4min(m, h4min(zlo, zhi));
        if (zp < 0 || !yIn || !gxin) m = HP4;
        return m;
    };

    stageWrite(z0 - 2, stageLoad(z0 - 2));
    stageWrite(z0 - 1, stageLoad(z0 - 1));
    stageWrite(z0,     stageLoad(z0));
    stageWrite(z0 + 1, stageLoad(z0 + 1));
    __syncthreads();
    H4u aT, a1, a2 = HP4;
    H4u e1m1 = e1compute(z0 - 1, aT);
    H4u e1c  = e1compute(z0, a1);
    __syncthreads();
    stageWrite(z0 + 2, stageLoad(z0 + 2));
    __syncthreads();

    H4u zmP = HN4;
    H4u skA = HZ4;
    float4 oA = ZERO4;
    double afd = 0.0, afs = 0.0;

    for (int z = z0; z <= z1; ++z) {
        const bool doStage = (z <= z1 - 2);
        H4u stv = doStage ? stageLoad(z + 3) : HP4;
        H4u skN = HZ4;
        float4 oN = ZERO4;
        if (z < z1 && uAct) {
            skN = *(const H4u*)(Sv + (size_t)z * ZS + gyo * YS + gx);
            oN  = *(const float4*)(Ov + (size_t)z * ZS + gyo * YS + gx);
        }

        H4u aC = HP4;
        H4u e1new = (z + 1 <= z1) ? e1compute(z + 1, aC) : HP4;

        H4u zm1w = HN4;
        if (z <= z1 - 1) {
            H4u t0 = (z >= 1) ? e1m1 : HN4;
            H4u t2 = (z + 1 < NZ) ? e1new : HN4;
            zm1w = h4max(t0, h4max(e1c, t2));
            if (!yIn || !gxin) zm1w = HN4;
            if (c < 14) ZM1[SLOT2(z)][lr][c] = zm1w;
        }

        const int p = z - 1;
        if (p >= z0 && p < z1) {
            H4u vm = h4max(ZM1[SLOT2(p)][rdn][cc],
                     h4max(zmP, ZM1[SLOT2(p)][rup][cc]));
            unsigned lw = __shfl_up(vm.hi, 1) >> 16;
            unsigned rx = __shfl_down(vm.lo, 1) & 0xFFFFu;
            if (xlo && c == 1)  lw = HNINF;
            if (xhi && c == 12) rx = HNINF;
            if (uAct) {
                H4u dilh = h4max(h4max(shl1(vm, lw), vm), shr1(vm, rx));
                H4u s = h4skel(skA, a2, dilh);
                float4 sf = h4_to_f4(s);
                afd += (double)(sf.x * oA.x + sf.y * oA.y +
                                sf.z * oA.z + sf.w * oA.w);
                afs += (double)(sf.x + sf.y + sf.z + sf.w);
            }
        }

        if (doStage) stageWrite(z + 3, stv);

        __syncthreads();
        e1m1 = e1c; e1c = e1new;
        a2 = a1; a1 = aC;
        zmP = zm1w;
        skA = skN; oA = oN;
    }

#pragma unroll
    for (int off = 32; off > 0; off >>= 1) {
        afd += __shfl_down(afd, off, 64);
        afs += __shfl_down(afs, off, 64);
    }
    int lane = tid & 63, wid = tid >> 6;
    if (lane == 0) { sred[wid * 2] = afd; sred[wid * 2 + 1] = afs; }
    __syncthreads();
    if (tid == 0) {
        double fd = sred[0] + sred[2] + sred[4] + sred[6];
        double fs = sred[1] + sred[3] + sred[5] + sred[7];
        if (v < 2) { atomicAdd(&sums[0], fd); atomicAdd(&sums[1], fs); }
        else       { atomicAdd(&sums[2], fd); atomicAdd(&sums[3], fs); }
    }
}

__global__ void final_kernel(const double* __restrict__ sums,
                             float* __restrict__ out) {
    if (threadIdx.x == 0 && blockIdx.x == 0) {
        const double SM = 1e-5;
        double tprec = (sums[0] + SM) / (sums[1] + SM);
        double tsens = (sums[2] + SM) / (sums[3] + SM);
        double cl = 2.0 * tprec * tsens / (tprec + tsens + SM);
        out[0] = (float)(1.0 - cl);
    }
}

extern "C" void kernel_launch(void* const* d_in, const int* in_sizes, int n_in,
                              void* d_out, int out_size, void* d_ws, size_t ws_size,
                              hipStream_t stream) {
    const float* pred = (const float*)d_in[0];
    const float* target = (const float*)d_in[1];
    float* out = (float*)d_out;

    _Float16* H0 = (_Float16*)d_ws;
    _Float16* H1 = H0 + NTOT;
    _Float16* skel = H1 + NTOT;
    double* sums = (double*)(skel + NTOT);

    hipMemsetAsync(sums, 0, 4 * sizeof(double), stream);

    dim3 dgrid(NX / TX, NY / TY2, NV * 6);   /* 4 x 16 x 24 = 1536 = 6/CU */

    fused2_kernel<true><<<dgrid, 256, 0, stream>>>(pred, target, H0, H0, skel);
    _Float16* A = H0;
    _Float16* B = H1;
    for (int j = 0; j < 24; ++j) {
        fused2_kernel<false><<<dgrid, 256, 0, stream>>>(pred, target, A, B, skel);
        _Float16* t = A; A = B; B = t;
    }
    last_kernel<<<dgrid, 256, 0, stream>>>(A, pred, target, skel, sums);

    final_kernel<<<1, 64, 0, stream>>>(sums, out);
}

// Round 13
// 1423.194 us; speedup vs baseline: 1.3346x; 1.0148x over previous
//
#include <hip/hip_runtime.h>
#include <math.h>

#define NX 192
#define NY 192
#define NZ 96
#define NV 4
#define VOL (NZ * NY * NX)      /* 3,538,944 */
#define NTOT (NV * VOL)         /* 14,155,776 */
#define YS NX
#define ZS (NY * NX)

#define TX 48
#define TY2 12
#define NG 14
#define R2A 18                   /* A rows: halo 3 */

#define ZCHM 24                  /* mid kernel: 4 z-chunks, grid 1024 = 4/CU */
#define ZCH2 16                  /* last kernel: 6 z-chunks, grid 1536 = 6/CU */

#define SLOT8(x) (((x) + 104) % 8)
#define SLOT4(x) (((x) + 100) % 4)
#define SLOT2(x) (((x) + 100) % 2)

#define HINF  0x7C00u
#define HNINF 0xFC00u

typedef _Float16 h2v __attribute__((ext_vector_type(2)));

struct __align__(8) H4u { unsigned lo, hi; };

__device__ __forceinline__ h2v h2_of(unsigned u) { return __builtin_bit_cast(h2v, u); }
__device__ __forceinline__ unsigned u_of(h2v h) { return __builtin_bit_cast(unsigned, h); }

__device__ __forceinline__ H4u h4min(H4u a, H4u b) {
    H4u r;
    r.lo = u_of(__builtin_elementwise_min(h2_of(a.lo), h2_of(b.lo)));
    r.hi = u_of(__builtin_elementwise_min(h2_of(a.hi), h2_of(b.hi)));
    return r;
}
__device__ __forceinline__ H4u h4max(H4u a, H4u b) {
    H4u r;
    r.lo = u_of(__builtin_elementwise_max(h2_of(a.lo), h2_of(b.lo)));
    r.hi = u_of(__builtin_elementwise_max(h2_of(a.hi), h2_of(b.hi)));
    return r;
}
__device__ __forceinline__ H4u h4add(H4u a, H4u b) {
    H4u r;
    r.lo = u_of(h2_of(a.lo) + h2_of(b.lo));
    r.hi = u_of(h2_of(a.hi) + h2_of(b.hi));
    return r;
}
__device__ __forceinline__ H4u h4sub(H4u a, H4u b) {
    H4u r;
    r.lo = u_of(h2_of(a.lo) - h2_of(b.lo));
    r.hi = u_of(h2_of(a.hi) - h2_of(b.hi));
    return r;
}
__device__ __forceinline__ H4u h4mul(H4u a, H4u b) {
    H4u r;
    r.lo = u_of(h2_of(a.lo) * h2_of(b.lo));
    r.hi = u_of(h2_of(a.hi) * h2_of(b.hi));
    return r;
}
/* skel update: s += max(relu(a-dil)*(1-s), 0), packed fp16 */
__device__ __forceinline__ H4u h4skel(H4u s, H4u a, H4u dil) {
    const H4u HZ4 = { 0u, 0u };
    const H4u HONE = { 0x3C003C00u, 0x3C003C00u };
    H4u dd = h4max(h4sub(a, dil), HZ4);
    H4u t = h4mul(dd, h4sub(HONE, s));
    return h4add(s, h4max(t, HZ4));
}
__device__ __forceinline__ H4u shl1(H4u c, unsigned p16) {
    H4u r;
    r.lo = (c.lo << 16) | (p16 & 0xFFFFu);
    r.hi = (c.hi << 16) | (c.lo >> 16);
    return r;
}
__device__ __forceinline__ H4u shr1(H4u c, unsigned n16) {
    H4u r;
    r.lo = (c.lo >> 16) | (c.hi << 16);
    r.hi = (c.hi >> 16) | ((n16 & 0xFFFFu) << 16);
    return r;
}
__device__ __forceinline__ H4u f4_to_h4(float4 f) {
    h2v a, b;
    a[0] = (_Float16)f.x; a[1] = (_Float16)f.y;
    b[0] = (_Float16)f.z; b[1] = (_Float16)f.w;
    H4u r; r.lo = u_of(a); r.hi = u_of(b); return r;
}
__device__ __forceinline__ float4 h4_to_f4(H4u h) {
    h2v a = h2_of(h.lo), b = h2_of(h.hi);
    return make_float4((float)a[0], (float)a[1], (float)b[0], (float)b[1]);
}

// ---------------- double-round kernel, 2 z-planes per super-step ----------
// Same dataflow as the r12-verified kernel, unrolled 2x in z. All stages
// read only previous-super-step LDS state; one barrier per super-step.
// Ring disjointness (mod): A N=8 writes{z+5,z+6} reads{z..z+3};
// E1c N=4 writes{z+1,z+2} reads{z-1,z}; ZM1 N=4 writes{z,z+1} reads{z-2,z-1};
// ZM2 N=4 writes{z-2,z-1} reads{z-4,z-3}.
template<bool FIRST>
__global__ __launch_bounds__(256, 4) void fused2x_kernel(
    const float* __restrict__ pred, const float* __restrict__ target,
    const _Float16* __restrict__ Ain, _Float16* __restrict__ Eout,
    _Float16* __restrict__ skel)
{
    __shared__ H4u As[8][R2A][NG];
    __shared__ H4u E1c[4][16][NG];
    __shared__ H4u ZM1[4][16][NG];
    __shared__ H4u ZM2[4][16][NG];

    const int tid = threadIdx.x;
    const int lr  = tid >> 4;
    const int c   = tid & 15;
    const int cc  = (c < 14) ? c : 13;
    const int sr  = tid / 14;
    const int sg  = tid - sr * 14;

    const int x0 = blockIdx.x * TX;
    const int y0 = blockIdx.y * TY2;
    const int v  = blockIdx.z / 4;
    const int ch = blockIdx.z % 4;
    const int z0 = ch * ZCHM;
    const int z1 = z0 + ZCHM;

    const float* Af = nullptr;
    const _Float16* Ah = nullptr;
    if (FIRST) Af = ((v < 2) ? pred : target) + (size_t)((v & 1) * 2 + 1) * VOL;
    else       Ah = Ain + (size_t)v * VOL;
    _Float16* Ev = Eout + (size_t)v * VOL;
    _Float16* Sv = skel + (size_t)v * VOL;

    const H4u HP4 = { 0x7C007C00u, 0x7C007C00u };
    const H4u HN4 = { 0xFC00FC00u, 0xFC00FC00u };
    const H4u HZ4 = { 0u, 0u };

    const bool xlo = (x0 == 0);
    const bool xhi = (x0 + TX == NX);

    const int  gys  = y0 - 3 + sr;
    const int  gxs  = x0 - 4 + 4 * sg;
    const bool stIn = (sr < R2A) && (gys >= 0) && (gys < NY) &&
                      (gxs >= 0) && (gxs < NX);

    const int  gx   = x0 - 4 + 4 * c;
    const bool gxin = (c < 14) && (gx >= 0) && (gx < NX);
    const int  gyo  = y0 - 2 + lr;
    const bool yIn  = (gyo >= 0) && (gyo < NY);
    const bool uAct = (lr >= 2 && lr <= 13 && c >= 1 && c <= 12);
    const int  rdn  = (lr > 0) ? lr - 1 : 0;
    const int  rup  = (lr < 15) ? lr + 1 : 15;

    auto stageLoad = [&](int za) -> H4u {
        H4u val = HP4;
        if (stIn && za >= 0 && za < NZ) {
            if (FIRST)
                val = f4_to_h4(*(const float4*)(Af + (size_t)za * ZS + gys * YS + gxs));
            else
                val = *(const H4u*)(Ah + (size_t)za * ZS + gys * YS + gxs);
        }
        return val;
    };
    auto stageWrite = [&](int za, H4u val) {
        if (sr < R2A) As[SLOT8(za)][sr][sg] = val;
    };

    /* E1(zp) at own row; writes E1c ring; captures A(zp) own-center */
    auto e1compute = [&](int zp, H4u& cenOut) -> H4u {
        if (zp >= NZ) { cenOut = HP4; return HP4; }
        const int s_c = SLOT8(zp), s_m = SLOT8(zp - 1), s_p = SLOT8(zp + 1);
        const bool hp = (zp + 1 < NZ);
        const int ar = lr + 1;
        H4u cen = As[s_c][ar][cc];
        H4u ylo = As[s_c][ar - 1][cc];
        H4u yhi = As[s_c][ar + 1][cc];
        H4u zlo = As[s_m][ar][cc];
        H4u zhi = hp ? As[s_p][ar][cc] : HP4;
        cenOut = cen;
        unsigned lw = __shfl_up(cen.hi, 1) >> 16;
        unsigned rx = __shfl_down(cen.lo, 1) & 0xFFFFu;
        if (c == 0) lw = HINF;
        H4u m = h4min(cen, shl1(cen, lw));
        m = h4min(m, shr1(cen, rx));
        m = h4min(m, h4min(ylo, yhi));
        m = h4min(m, h4min(zlo, zhi));
        if (zp < 0 || !yIn || !gxin) m = HP4;
        if (c < 14) E1c[SLOT4(zp)][lr][c] = m;
        return m;
    };

    /* erode E1-regs -> E2 at own cell; optional global write */
    auto e2compute = [&](int p, H4u cen, H4u zlo, H4u zhi) -> H4u {
        H4u ylo = E1c[SLOT4(p)][rdn][cc];
        H4u yhi = E1c[SLOT4(p)][rup][cc];
        unsigned lwE = __shfl_up(cen.hi, 1) >> 16;
        unsigned rxE = __shfl_down(cen.lo, 1) & 0xFFFFu;
        if (c == 0) lwE = HINF;
        H4u m2 = h4min(cen, shl1(cen, lwE));
        m2 = h4min(m2, shr1(cen, rxE));
        m2 = h4min(m2, h4min(ylo, yhi));
        m2 = h4min(m2, h4min(zlo, zhi));
        H4u res = HN4;
        if (yIn && gxin) {
            res = m2;
            if (p >= z0 && p < z1 && lr >= 2 && lr <= 13 && c >= 1 && c <= 12)
                *(H4u*)(Ev + (size_t)p * ZS + gyo * YS + gx) = m2;
        }
        return res;
    };

    auto dilateX = [&](H4u vm) -> H4u {
        unsigned lw = __shfl_up(vm.hi, 1) >> 16;
        unsigned rx = __shfl_down(vm.lo, 1) & 0xFFFFu;
        if (xlo && c == 1)  lw = HNINF;
        if (xhi && c == 12) rx = HNINF;
        return h4max(h4max(shl1(vm, lw), vm), shr1(vm, rx));
    };

    // ---- prologue: A(z0-3..z0+4), E1(z0-2..z0) ----
    stageWrite(z0 - 3, stageLoad(z0 - 3));
    stageWrite(z0 - 2, stageLoad(z0 - 2));
    stageWrite(z0 - 1, stageLoad(z0 - 1));
    stageWrite(z0,     stageLoad(z0));
    __syncthreads();
    H4u aDump, aPa, aPb;
    H4u eP2b = e1compute(z0 - 2, aDump);
    H4u eP1a = e1compute(z0 - 1, aPa);
    stageWrite(z0 + 1, stageLoad(z0 + 1));
    stageWrite(z0 + 2, stageLoad(z0 + 2));
    stageWrite(z0 + 3, stageLoad(z0 + 3));
    stageWrite(z0 + 4, stageLoad(z0 + 4));
    __syncthreads();
    H4u eP1b = e1compute(z0, aPb);
    __syncthreads();

    /* register pair-chains (suffix a = lower plane, b = upper) */
    H4u e1P3a = HP4, e1P3b = HP4;            /* E1(z-5), E1(z-4) */
    H4u e1P2a = HP4, e1P2b = eP2b;           /* E1(z-3), E1(z-2) */
    H4u e1P1a = eP1a, e1P1b = eP1b;          /* E1(z-1), E1(z)   */
    H4u aP2a = HP4, aP2b = HP4;              /* A(z-3), A(z-2)   */
    H4u aP1a = aPa, aP1b = aPb;              /* A(z-1), A(z)     */
    H4u e2Pa = HN4, e2Pb = HN4;              /* E2(z-3), E2(z-2) */
    H4u zm1Pa = HN4, zm1Pb = HN4;            /* zm1(z-2), zm1(z-1) */
    H4u zm2Pa = HN4, zm2Pb = HN4;            /* zm2(z-4), zm2(z-3) */
    H4u skPa = HZ4, skPb = HZ4;              /* skel(z-2), skel(z-1) */
    H4u sqPa = HZ4, sqPb = HZ4;              /* s'(z-4), s'(z-3) */

    // ---- main loop: one barrier per super-step (2 planes) ----
    for (int z = z0; z <= z1 + 2; z += 2) {
        /* early global loads */
        H4u stv5 = (z + 5 <= z1 + 2) ? stageLoad(z + 5) : HP4;
        H4u stv6 = (z + 6 <= z1 + 2) ? stageLoad(z + 6) : HP4;
        H4u skNa = HZ4, skNb = HZ4;
        if (!FIRST && uAct) {
            if (z < z1)
                skNa = *(const H4u*)(Sv + (size_t)z * ZS + gyo * YS + gx);
            if (z + 1 < z1)
                skNb = *(const H4u*)(Sv + (size_t)(z + 1) * ZS + gyo * YS + gx);
        }

        /* e1 pair: planes z+1, z+2 */
        H4u aA = HP4, aB = HP4;
        H4u e1A = (z + 1 <= z1 + 1) ? e1compute(z + 1, aA) : HP4;
        H4u e1B = (z + 2 <= z1 + 1) ? e1compute(z + 2, aB) : HP4;

        /* zm1 pair: planes z, z+1 */
        H4u zm1a, zm1b;
        {
            H4u t0 = (z >= 1) ? e1P1a : HN4;
            H4u t2 = (z + 1 < NZ) ? e1A : HN4;
            zm1a = h4max(t0, h4max(e1P1b, t2));
            H4u t2b = (z + 2 < NZ) ? e1B : HN4;
            zm1b = h4max(e1P1b, h4max(e1A, t2b));
            if (!yIn || !gxin) { zm1a = HN4; zm1b = HN4; }
            if (c < 14) {
                ZM1[SLOT4(z)][lr][c] = zm1a;
                ZM1[SLOT4(z + 1)][lr][c] = zm1b;
            }
        }

        /* e2 pair: planes z-1, z */
        H4u e2A = HN4, e2B = HN4;
        if (z - 1 >= 0 && z - 1 <= z1 && z - 1 < NZ)
            e2A = e2compute(z - 1, e1P1a, e1P2b, e1P1b);
        if (z >= 0 && z <= z1 && z < NZ)
            e2B = e2compute(z, e1P1b, e1P1a, e1A);

        /* zm2 pair: planes z-2, z-1 (E2 chain z-3..z) */
        H4u zm2a = h4max(e2Pa, h4max(e2Pb, e2A));
        H4u zm2b = h4max(e2Pb, h4max(e2A, e2B));
        if (c < 14) {
            ZM2[SLOT4(z - 2)][lr][c] = zm2a;
            ZM2[SLOT4(z - 1)][lr][c] = zm2b;
        }

        /* upd1 pair: planes z-2, z-1 */
        H4u spA = HZ4, spB = HZ4;
        if (z - 2 >= z0 && z - 2 < z1) {
            H4u vm = h4max(ZM1[SLOT4(z - 2)][rdn][cc],
                     h4max(zm1Pa, ZM1[SLOT4(z - 2)][rup][cc]));
            H4u dil = dilateX(vm);
            if (uAct) spA = h4skel(skPa, aP2b, dil);
        }
        if (z - 1 >= z0 && z - 1 < z1) {
            H4u vm = h4max(ZM1[SLOT4(z - 1)][rdn][cc],
                     h4max(zm1Pb, ZM1[SLOT4(z - 1)][rup][cc]));
            H4u dil = dilateX(vm);
            if (uAct) spB = h4skel(skPb, aP1a, dil);
        }

        /* upd2 pair: planes z-4, z-3; skel store */
        if (z - 4 >= z0 && z - 4 < z1) {
            H4u vm2 = h4max(ZM2[SLOT4(z - 4)][rdn][cc],
                      h4max(zm2Pa, ZM2[SLOT4(z - 4)][rup][cc]));
            H4u dil = dilateX(vm2);
            if (uAct) {
                H4u s = h4skel(sqPa, e1P3b, dil);
                *(H4u*)(Sv + (size_t)(z - 4) * ZS + gyo * YS + gx) = s;
            }
        }
        if (z - 3 >= z0 && z - 3 < z1) {
            H4u vm2 = h4max(ZM2[SLOT4(z - 3)][rdn][cc],
                      h4max(zm2Pb, ZM2[SLOT4(z - 3)][rup][cc]));
            H4u dil = dilateX(vm2);
            if (uAct) {
                H4u s = h4skel(sqPb, e1P2a, dil);
                *(H4u*)(Sv + (size_t)(z - 3) * ZS + gyo * YS + gx) = s;
            }
        }

        /* commit staged A planes */
        if (z + 5 <= z1 + 2) stageWrite(z + 5, stv5);
        if (z + 6 <= z1 + 2) stageWrite(z + 6, stv6);

        __syncthreads();
        /* rotations */
        e1P3a = e1P2a; e1P3b = e1P2b;
        e1P2a = e1P1a; e1P2b = e1P1b;
        e1P1a = e1A;   e1P1b = e1B;
        aP2a = aP1a; aP2b = aP1b;
        aP1a = aA;   aP1b = aB;
        e2Pa = e2A; e2Pb = e2B;
        zm1Pa = zm1a; zm1Pb = zm1b;
        zm2Pa = zm2a; zm2Pb = zm2b;
        skPa = skNa; skPb = skNb;
        sqPa = spA; sqPb = spB;
    }
}

// ---------------- LAST kernel (round 50 + fused reduction) — r12 verified --
__global__ __launch_bounds__(256, 6) void last_kernel(
    const _Float16* __restrict__ Ain,
    const float* __restrict__ pred, const float* __restrict__ target,
    const _Float16* __restrict__ skel, double* __restrict__ sums)
{
    __shared__ H4u As[4][R2A][NG];
    __shared__ H4u ZM1[2][16][NG];
    __shared__ double sred[8];

    const int tid = threadIdx.x;
    const int lr  = tid >> 4;
    const int c   = tid & 15;
    const int cc  = (c < 14) ? c : 13;
    const int sr  = tid / 14;
    const int sg  = tid - sr * 14;

    const int x0 = blockIdx.x * TX;
    const int y0 = blockIdx.y * TY2;
    const int v  = blockIdx.z / 6;
    const int ch = blockIdx.z % 6;
    const int z0 = ch * ZCH2;
    const int z1 = z0 + ZCH2;

    const _Float16* Ah = Ain + (size_t)v * VOL;
    const _Float16* Sv = skel + (size_t)v * VOL;
    const float* Ov = ((v < 2) ? target : pred) + (size_t)((v & 1) * 2 + 1) * VOL;

    const H4u HP4 = { 0x7C007C00u, 0x7C007C00u };
    const H4u HN4 = { 0xFC00FC00u, 0xFC00FC00u };
    const H4u HZ4 = { 0u, 0u };
    const float4 ZERO4 = make_float4(0.f, 0.f, 0.f, 0.f);

    const bool xlo = (x0 == 0);
    const bool xhi = (x0 + TX == NX);

    const int  gys  = y0 - 3 + sr;
    const int  gxs  = x0 - 4 + 4 * sg;
    const bool stIn = (sr < R2A) && (gys >= 0) && (gys < NY) &&
                      (gxs >= 0) && (gxs < NX);

    const int  gx   = x0 - 4 + 4 * c;
    const bool gxin = (c < 14) && (gx >= 0) && (gx < NX);
    const int  gyo  = y0 - 2 + lr;
    const bool yIn  = (gyo >= 0) && (gyo < NY);
    const bool uAct = (lr >= 2 && lr <= 13 && c >= 1 && c <= 12);
    const int  rdn  = (lr > 0) ? lr - 1 : 0;
    const int  rup  = (lr < 15) ? lr + 1 : 15;

    auto stageLoad = [&](int za) -> H4u {
        H4u val = HP4;
        if (stIn && za >= 0 && za < NZ)
            val = *(const H4u*)(Ah + (size_t)za * ZS + gys * YS + gxs);
        return val;
    };
    auto stageWrite = [&](int za, H4u val) {
        if (sr < R2A) As[SLOT4(za)][sr][sg] = val;
    };

    auto e1compute = [&](int zp, H4u& cenOut) -> H4u {
        if (zp >= NZ) { cenOut = HP4; return HP4; }
        const int s_c = SLOT4(zp), s_m = SLOT4(zp - 1), s_p = SLOT4(zp + 1);
        const bool hp = (zp + 1 < NZ);
        const int ar = lr + 1;
        H4u cen = As[s_c][ar][cc];
        H4u ylo = As[s_c][ar - 1][cc];
        H4u yhi = As[s_c][ar + 1][cc];
        H4u zlo = As[s_m][ar][cc];
        H4u zhi = hp ? As[s_p][ar][cc] : HP4;
        cenOut = cen;
        unsigned lw = __shfl_up(cen.hi, 1) >> 16;
        unsigned rx = __shfl_down(cen.lo, 1) & 0xFFFFu;
        if (c == 0) lw = HINF;
        H4u m = h4min(cen, shl1(cen, lw));
        m = h4min(m, shr1(cen, rx));
        m = h4min(m, h4min(ylo, yhi));
        m = h4min(m, h4min(zlo, zhi));
        if (zp < 0 || !yIn || !gxin) m = HP4;
        return m;
    };

    stageWrite(z0 - 2, stageLoad(z0 - 2));
    stageWrite(z0 - 1, stageLoad(z0 - 1));
    stageWrite(z0,     stageLoad(z0));
    stageWrite(z0 + 1, stageLoad(z0 + 1));
    __syncthreads();
    H4u aT, a1, a2 = HP4;
    H4u e1m1 = e1compute(z0 - 1, aT);
    H4u e1c  = e1compute(z0, a1);
    __syncthreads();
    stageWrite(z0 + 2, stageLoad(z0 + 2));
    __syncthreads();

    H4u zmP = HN4;
    H4u skA = HZ4;
    float4 oA = ZERO4;
    double afd = 0.0, afs = 0.0;

    for (int z = z0; z <= z1; ++z) {
        const bool doStage = (z <= z1 - 2);
        H4u stv = doStage ? stageLoad(z + 3) : HP4;
        H4u skN = HZ4;
        float4 oN = ZERO4;
        if (z < z1 && uAct) {
            skN = *(const H4u*)(Sv + (size_t)z * ZS + gyo * YS + gx);
            oN  = *(const float4*)(Ov + (size_t)z * ZS + gyo * YS + gx);
        }

        H4u aC = HP4;
        H4u e1new = (z + 1 <= z1) ? e1compute(z + 1, aC) : HP4;

        H4u zm1w = HN4;
        if (z <= z1 - 1) {
            H4u t0 = (z >= 1) ? e1m1 : HN4;
            H4u t2 = (z + 1 < NZ) ? e1new : HN4;
            zm1w = h4max(t0, h4max(e1c, t2));
            if (!yIn || !gxin) zm1w = HN4;
            if (c < 14) ZM1[SLOT2(z)][lr][c] = zm1w;
        }

        const int p = z - 1;
        if (p >= z0 && p < z1) {
            H4u vm = h4max(ZM1[SLOT2(p)][rdn][cc],
                     h4max(zmP, ZM1[SLOT2(p)][rup][cc]));
            unsigned lw = __shfl_up(vm.hi, 1) >> 16;
            unsigned rx = __shfl_down(vm.lo, 1) & 0xFFFFu;
            if (xlo && c == 1)  lw = HNINF;
            if (xhi && c == 12) rx = HNINF;
            if (uAct) {
                H4u dilh = h4max(h4max(shl1(vm, lw), vm), shr1(vm, rx));
                H4u s = h4skel(skA, a2, dilh);
                float4 sf = h4_to_f4(s);
                afd += (double)(sf.x * oA.x + sf.y * oA.y +
                                sf.z * oA.z + sf.w * oA.w);
                afs += (double)(sf.x + sf.y + sf.z + sf.w);
            }
        }

        if (doStage) stageWrite(z + 3, stv);

        __syncthreads();
        e1m1 = e1c; e1c = e1new;
        a2 = a1; a1 = aC;
        zmP = zm1w;
        skA = skN; oA = oN;
    }

#pragma unroll
    for (int off = 32; off > 0; off >>= 1) {
        afd += __shfl_down(afd, off, 64);
        afs += __shfl_down(afs, off, 64);
    }
    int lane = tid & 63, wid = tid >> 6;
    if (lane == 0) { sred[wid * 2] = afd; sred[wid * 2 + 1] = afs; }
    __syncthreads();
    if (tid == 0) {
        double fd = sred[0] + sred[2] + sred[4] + sred[6];
        double fs = sred[1] + sred[3] + sred[5] + sred[7];
        if (v < 2) { atomicAdd(&sums[0], fd); atomicAdd(&sums[1], fs); }
        else       { atomicAdd(&sums[2], fd); atomicAdd(&sums[3], fs); }
    }
}

__global__ void final_kernel(const double* __restrict__ sums,
                             float* __restrict__ out) {
    if (threadIdx.x == 0 && blockIdx.x == 0) {
        const double SM = 1e-5;
        double tprec = (sums[0] + SM) / (sums[1] + SM);
        double tsens = (sums[2] + SM) / (sums[3] + SM);
        double cl = 2.0 * tprec * tsens / (tprec + tsens + SM);
        out[0] = (float)(1.0 - cl);
    }
}

extern "C" void kernel_launch(void* const* d_in, const int* in_sizes, int n_in,
                              void* d_out, int out_size, void* d_ws, size_t ws_size,
                              hipStream_t stream) {
    const float* pred = (const float*)d_in[0];
    const float* target = (const float*)d_in[1];
    float* out = (float*)d_out;

    _Float16* H0 = (_Float16*)d_ws;
    _Float16* H1 = H0 + NTOT;
    _Float16* skel = H1 + NTOT;
    double* sums = (double*)(skel + NTOT);

    hipMemsetAsync(sums, 0, 4 * sizeof(double), stream);

    dim3 mgrid(NX / TX, NY / TY2, NV * 4);   /* 4 x 16 x 16 = 1024 = 4/CU */
    dim3 lgrid(NX / TX, NY / TY2, NV * 6);   /* 4 x 16 x 24 = 1536 = 6/CU */

    /* rounds 0,1: FIRST (reads pred/target channels directly) */
    fused2x_kernel<true><<<mgrid, 256, 0, stream>>>(pred, target, H0, H0, skel);
    /* rounds 2..49: 24 double launches */
    _Float16* A = H0;
    _Float16* B = H1;
    for (int j = 0; j < 24; ++j) {
        fused2x_kernel<false><<<mgrid, 256, 0, stream>>>(pred, target, A, B, skel);
        _Float16* t = A; A = B; B = t;
    }
    /* round 50 + fused reduction */
    last_kernel<<<lgrid, 256, 0, stream>>>(A, pred, target, skel, sums);

    final_kernel<<<1, 64, 0, stream>>>(sums, out);
}